// Round 1
// 63.740 us; speedup vs baseline: 1.0437x; 1.0437x over previous
//
#include <hip/hip_runtime.h>

#define IN_CH 16
#define OUT_CH 32
#define NUM_INPUTS 144   // IN_CH * 3 * 3
#define H_ 32
#define W_ 32

typedef __attribute__((ext_vector_type(2))) float f32x2;
typedef __attribute__((ext_vector_type(4))) float f32x4;

// ---------------------------------------------------------------------------
// R7: och-on-lanes restructure.
//
// Old structure: tables broadcast per tap (b128+b64 serving 4 outputs) at
// 2 waves/SIMD -> latency-bound, ~0.83 LDS instr/pair-op, ~26us kernel.
//
// New: grid 512 blocks x 512 thr (8 waves). Block = 16 spatial positions
// (2 rows x 8 cols) x ALL 32 och. Lane = sg(4 position groups) x op(16
// och-pairs). Wave = 2 input channels (tap-split 8-way, LDS reduction).
//   - table read ltA[i*16+op] (b128: p1 pair + m0 pair) + ltD (b64: dm pair)
//     is lane-varying: ONE read pair per tap serves 4 pos x 32 och = 512
//     pair-ops (was 4).
//   - patch rows read once per (c,row) as aligned b128+b64 (6 cols), all 9
//     (kh,kw) windows resolved by static register indexing.
//   - y(x) = m0*x + b0 + dm*max(x-p1,0)  (exact clipped-tail identity);
//     Sum_i b0 folded into per-och constant B0 at build time.
//   - reduction buffer ALIASES ltA (tables dead after main loop) -> static
//     LDS 63,616 B < 64KB -> 2 blocks/CU -> 16 waves/CU = 4/SIMD.
// ---------------------------------------------------------------------------
__global__ __launch_bounds__(512, 4) void apc_fused(
        const float* __restrict__ x,
        const float* __restrict__ pos,
        const float* __restrict__ val,
        float* __restrict__ out) {
    __shared__ f32x4 ltA[NUM_INPUTS * 16];   // 36864 B  (p1a,p1b,m0a,m0b)
    __shared__ f32x2 ltD[NUM_INPUTS * 16];   // 18432 B  (dma,dmb)
    __shared__ float lx[IN_CH * 4 * 16];     //  4096 B  padded 2x8 tile
    __shared__ f32x2 bpart[512];             //  4096 B  b0 partials
    __shared__ f32x2 B0f[16];                //   128 B  Sum_i b0 per och-pair
    // reduction buffer (16 KB) aliases ltA after the main loop.

    int tid  = threadIdx.x;
    int bx   = blockIdx.x;           // 0..511
    int b    = bx >> 6;              // batch
    int t64  = bx & 63;              // 16 row-pairs x 4 col-octets
    int row0 = (t64 >> 2) * 2;
    int col0 = (t64 & 3) * 8;

    // ---- Phase 0a: stage 16ch x 4rows x 10cols (stride 16), zero-padded. --
    #pragma unroll
    for (int it = 0; it < 2; ++it) {
        int s  = tid + it * 512;
        int c  = s >> 6;
        int rr = (s >> 4) & 3;       // padded row: global row0+rr-1
        int cl = s & 15;             // padded col: global col0+cl-1
        int gr = row0 + rr - 1;
        int gc = col0 + cl - 1;
        float v = 0.f;
        if (cl < 10 && (unsigned)gr < (unsigned)H_ && (unsigned)gc < (unsigned)W_)
            v = x[((b * IN_CH + c) * H_ + gr) * W_ + gc];
        lx[s] = v;
    }

    // ---- Phase 0b: build tables. thread = (i-group, och-pair op). ---------
    {
        int opb = tid & 15;          // och pair (2*opb, 2*opb+1)
        int ib  = tid >> 4;          // i = ib + 32k
        f32x2 bs = {0.f, 0.f};
        #pragma unroll
        for (int k = 0; k < 5; ++k) {
            int i = ib + 32 * k;
            if (i < NUM_INPUTS) {
                const float* pp = pos + i * 96 + opb * 6;  // 6 consecutive
                const float* vv = val + i * 96 + opb * 6;
                float q0a = pp[0], q1a = pp[1], q2a = pp[2];
                float q0b = pp[3], q1b = pp[4], q2b = pp[5];
                float w0a = vv[0], w1a = vv[1], w2a = vv[2];
                float w0b = vv[3], w1b = vv[4], w2b = vv[5];
                float s0a = (w1a - w0a) * __builtin_amdgcn_rcpf(q1a - q0a);
                float s1a = (w2a - w1a) * __builtin_amdgcn_rcpf(q2a - q1a);
                float s0b = (w1b - w0b) * __builtin_amdgcn_rcpf(q1b - q0b);
                float s1b = (w2b - w1b) * __builtin_amdgcn_rcpf(q2b - q1b);
                ltA[i * 16 + opb] = (f32x4){q1a, q1b, s0a, s0b};
                ltD[i * 16 + opb] = (f32x2){s1a - s0a, s1b - s0b};
                bs.x += w0a - s0a * q0a;    // b0 = w0 - s0*q0
                bs.y += w0b - s0b * q0b;
            }
        }
        bpart[tid] = bs;
    }
    __syncthreads();

    // B0f[op] = Sum over all 144 taps of b0 (lanes 0..15 of wave 0).
    if (tid < 16) {
        f32x2 s = {0.f, 0.f};
        #pragma unroll
        for (int g2 = 0; g2 < 32; ++g2) s += bpart[g2 * 16 + tid];
        B0f[tid] = s;
    }

    // ---- Main loop: wave = channels {2w,2w+1}; lane = (sg, op). -----------
    int wid  = tid >> 6;             // 0..7
    int lane = tid & 63;
    int sg   = lane >> 4;            // position group
    int op   = lane & 15;            // och pair
    int r0   = sg >> 1;              // local output row 0/1
    int cb   = (sg & 1) * 4;         // col base 0/4
    int c0   = wid * 2;

    f32x2 aacc[4], hacc[4];
    const f32x2 zz = {0.f, 0.f};
    #pragma unroll
    for (int j = 0; j < 4; ++j) { aacc[j] = zz; hacc[j] = zz; }

    const float* lxb = lx + (c0 * 4 + r0) * 16 + cb;   // 16B-aligned
    const f32x4* Ab  = ltA + c0 * 144 + op;
    const f32x2* Db  = ltD + c0 * 144 + op;

    #pragma unroll
    for (int dc = 0; dc < 2; ++dc) {
        // preload 3 padded rows x 6 cols -> covers all (kh,kw,j) windows
        float w[3][6];
        #pragma unroll
        for (int dr = 0; dr < 3; ++dr) {
            f32x4 u = *(const f32x4*)(lxb + (dc * 4 + dr) * 16);
            f32x2 v = *(const f32x2*)(lxb + (dc * 4 + dr) * 16 + 4);
            w[dr][0] = u.x; w[dr][1] = u.y; w[dr][2] = u.z; w[dr][3] = u.w;
            w[dr][4] = v.x; w[dr][5] = v.y;
        }
        #pragma unroll
        for (int kh = 0; kh < 3; ++kh) {
            #pragma unroll
            for (int kw = 0; kw < 3; ++kw) {
                int ti = (dc * 9 + kh * 3 + kw) * 16;  // compile-time offset
                f32x4 A = Ab[ti];
                f32x2 D = Db[ti];
                f32x2 P = {A.x, A.y};
                f32x2 M = {A.z, A.w};
                #pragma unroll
                for (int j = 0; j < 4; ++j) {
                    f32x2 q = {w[kh][kw + j], w[kh][kw + j]};
                    aacc[j] = __builtin_elementwise_fma(M, q, aacc[j]);
                    hacc[j] = __builtin_elementwise_fma(
                        D, __builtin_elementwise_max(q - P, zz), hacc[j]);
                }
            }
        }
    }

    // ---- Tap-split combine: red aliases ltA (tables dead now). ------------
    __syncthreads();                 // all table/lx reads complete
    {
        f32x2 s0 = aacc[0] + hacc[0], s1 = aacc[1] + hacc[1];
        f32x2 s2 = aacc[2] + hacc[2], s3 = aacc[3] + hacc[3];
        int rb = (wid * 64 + lane) * 2;
        ltA[rb + 0] = (f32x4){s0.x, s0.y, s1.x, s1.y};
        ltA[rb + 1] = (f32x4){s2.x, s2.y, s3.x, s3.y};
    }
    __syncthreads();

    if (tid < 256) {
        const f32x2* red = (const f32x2*)ltA;
        int opx = tid >> 4;          // och pair
        int p   = tid & 15;          // position (cols fastest -> coalesced)
        int rr  = p >> 3;
        int cl  = p & 7;
        int sgx = rr * 2 + (cl >> 2);
        int j   = cl & 3;
        int base = (sgx * 16 + opx) * 4 + j;
        f32x2 s = B0f[opx];
        #pragma unroll
        for (int wv = 0; wv < 8; ++wv) s += red[wv * 256 + base];
        int oidx = ((b * OUT_CH + 2 * opx) * H_ + (row0 + rr)) * W_ + (col0 + cl);
        out[oidx]            = s.x;
        out[oidx + H_ * W_]  = s.y;
    }
}

extern "C" void kernel_launch(void* const* d_in, const int* in_sizes, int n_in,
                              void* d_out, int out_size, void* d_ws, size_t ws_size,
                              hipStream_t stream) {
    const float* x   = (const float*)d_in[0];
    const float* pos = (const float*)d_in[1];
    const float* val = (const float*)d_in[2];

    apc_fused<<<dim3(512), dim3(512), 0, stream>>>(x, pos, val, (float*)d_out);
}